// Round 6
// baseline (138.004 us; speedup 1.0000x reference)
//
#include <hip/hip_runtime.h>

#define NLOG2E -1.44269504088896340736f

// K1 (1 thread): fold weight algebra into 69 floats in d_ws.
// K2: persistent grid-stride kernel, 4 rows/iter, prefetch-by-one so the
//     ~900-cyc HBM latency of iter i+1's x-loads hides under iter i's
//     ~350-cyc compute across 4 resident waves/SIMD.
// Constants read via uniform pointer -> s_load -> SGPRs (no VGPR cost).
//
// ws layout (floats): [0:8)=uw0 [8:16)=uw1 [16:24)=ub [24:56)=w2f
//                     [56:60)=b2 [60:64)=ncl2 [64:68)=aw2 [68]=bb3

__global__ void prefold_kernel(
    const float* __restrict__ W1, const float* __restrict__ b1,
    const float* __restrict__ a1, const float* __restrict__ c1,
    const float* __restrict__ W2, const float* __restrict__ b2,
    const float* __restrict__ a2, const float* __restrict__ c2,
    const float* __restrict__ W3, const float* __restrict__ b3,
    float* __restrict__ C)
{
    if (threadIdx.x == 0 && blockIdx.x == 0) {
        for (int j = 0; j < 8; ++j) {
            float ncl = c1[j] * NLOG2E;
            C[j]      = W1[j]     * ncl;
            C[8 + j]  = W1[8 + j] * ncl;
            C[16 + j] = b1[j]     * ncl;
            float k1 = a1[j] / ncl;
            for (int k = 0; k < 4; ++k)
                C[24 + j * 4 + k] = W2[j * 4 + k] * k1;
        }
        for (int k = 0; k < 4; ++k) {
            C[56 + k] = b2[k];
            C[60 + k] = c2[k] * NLOG2E;
            C[64 + k] = a2[k] * W3[k];
        }
        C[68] = b3[0];
    }
}

__global__ __launch_bounds__(256, 4) void PlaygroundModel_66365834658304_kernel(
    const float* __restrict__ x, const float* __restrict__ C,
    float* __restrict__ out, int units, int rows, int T)
{
    const float* uw0  = C;
    const float* uw1  = C + 8;
    const float* ub   = C + 16;
    const float* w2f  = C + 24;
    const float* bb2  = C + 56;
    const float* ncl2 = C + 60;
    const float* aw2  = C + 64;
    float bb3 = C[68];

    int tid = blockIdx.x * blockDim.x + threadIdx.x;
    const float4* x4 = (const float4*)x;
    float4* o4 = (float4*)out;

    int u = tid;
    float4 n0, n1;
    if (u < units) {                       // prime the pipeline
        n0 = x4[(size_t)u * 2 + 0];
        n1 = x4[(size_t)u * 2 + 1];
    }
    while (u < units) {
        float4 c0 = n0, c1 = n1;
        int nu = u + T;
        if (nu < units) {                  // prefetch next iteration
            n0 = x4[(size_t)nu * 2 + 0];
            n1 = x4[(size_t)nu * 2 + 1];
        }

        float X0[4] = {c0.x, c0.z, c1.x, c1.z};
        float X1[4] = {c0.y, c0.w, c1.y, c1.w};

        // stage 1: 32 independent u-values
        float uv[4][8];
#pragma unroll
        for (int r = 0; r < 4; ++r)
#pragma unroll
            for (int j = 0; j < 8; ++j)
                uv[r][j] = fmaf(X0[r], uw0[j], fmaf(X1[r], uw1[j], ub[j]));

        // stage 2: 32 independent exp2/add/rcp/mul chains
#pragma unroll
        for (int r = 0; r < 4; ++r)
#pragma unroll
            for (int j = 0; j < 8; ++j) {
                float e = __builtin_amdgcn_exp2f(uv[r][j]);
                float s = __builtin_amdgcn_rcpf(1.0f + e);
                uv[r][j] = uv[r][j] * s;   // h_eff
            }

        // stage 3: 16 independent dot-8
        float t2[4][4];
#pragma unroll
        for (int r = 0; r < 4; ++r)
#pragma unroll
            for (int k = 0; k < 4; ++k) {
                float t = bb2[k];
#pragma unroll
                for (int j = 0; j < 8; ++j)
                    t = fmaf(uv[r][j], w2f[j * 4 + k], t);
                t2[r][k] = t;
            }

        // stage 4: 16 independent activations, then reduce
        float res[4];
#pragma unroll
        for (int r = 0; r < 4; ++r) {
            float s2[4];
#pragma unroll
            for (int k = 0; k < 4; ++k) {
                float u2 = ncl2[k] * t2[r][k];
                s2[k] = __builtin_amdgcn_rcpf(
                            1.0f + __builtin_amdgcn_exp2f(u2));
            }
            float o = bb3;
#pragma unroll
            for (int k = 0; k < 4; ++k)
                o = fmaf(t2[r][k] * s2[k], aw2[k], o);
            res[r] = o;
        }
        o4[u] = make_float4(res[0], res[1], res[2], res[3]);
        u = nu;
    }

    // scalar tail for rows % 4 != 0 (not hit for B = 8388608)
    if (tid == 0) {
        for (long long rr = (long long)units * 4; rr < rows; ++rr) {
            float x0 = x[rr * 2 + 0], x1 = x[rr * 2 + 1];
            float h[8];
#pragma unroll
            for (int j = 0; j < 8; ++j) {
                float uu = fmaf(x0, uw0[j], fmaf(x1, uw1[j], ub[j]));
                float s  = __builtin_amdgcn_rcpf(
                               1.0f + __builtin_amdgcn_exp2f(uu));
                h[j] = uu * s;
            }
            float o = bb3;
#pragma unroll
            for (int k = 0; k < 4; ++k) {
                float t = bb2[k];
#pragma unroll
                for (int j = 0; j < 8; ++j) t = fmaf(h[j], w2f[j * 4 + k], t);
                float u2 = ncl2[k] * t;
                float sg = __builtin_amdgcn_rcpf(
                               1.0f + __builtin_amdgcn_exp2f(u2));
                o = fmaf(t * sg, aw2[k], o);
            }
            out[rr] = o;
        }
    }
}

extern "C" void kernel_launch(void* const* d_in, const int* in_sizes, int n_in,
                              void* d_out, int out_size, void* d_ws, size_t ws_size,
                              hipStream_t stream) {
    const float* x  = (const float*)d_in[0];
    const float* W1 = (const float*)d_in[1];
    const float* b1 = (const float*)d_in[2];
    const float* a1 = (const float*)d_in[3];
    const float* c1 = (const float*)d_in[4];
    const float* W2 = (const float*)d_in[5];
    const float* b2 = (const float*)d_in[6];
    const float* a2 = (const float*)d_in[7];
    const float* c2 = (const float*)d_in[8];
    const float* W3 = (const float*)d_in[9];
    const float* b3 = (const float*)d_in[10];
    float* out = (float*)d_out;
    float* C   = (float*)d_ws;

    prefold_kernel<<<1, 64, 0, stream>>>(W1, b1, a1, c1, W2, b2, a2, c2,
                                         W3, b3, C);

    int rows  = in_sizes[0] / 2;
    int units = rows / 4;                  // 4 rows per unit
    int block = 256;
    int grid  = 1024;                      // 4 waves/SIMD resident, persistent
    int T     = grid * block;

    PlaygroundModel_66365834658304_kernel<<<grid, block, 0, stream>>>(
        x, C, out, units, rows, T);
}

// Round 7
// 129.545 us; speedup vs baseline: 1.0653x; 1.0653x over previous
//
#include <hip/hip_runtime.h>

#define NLOG2E -1.44269504088896340736f

// K1 (1 thread): fold weight algebra into 69 floats in d_ws.
// K2: one-shot, 4 rows/thread, stage-batched. Sigmoid denominators are
//     inverted in groups of 4 via product-tree: 1 v_rcp + 11 v_mul replaces
//     4 v_rcp (exact algebra; tests/exploits the gfx950 trans-pipe rate).
//     exp2 input clamped at +30 so the 4-way denominator product can't
//     overflow f32 (h_eff error at clamp < 3e-8; negative side untouched).
//
// ws layout (floats): [0:8)=uw0 [8:16)=uw1 [16:24)=ub [24:56)=w2f
//                     [56:60)=b2 [60:64)=ncl2 [64:68)=aw2 [68]=bb3

__global__ void prefold_kernel(
    const float* __restrict__ W1, const float* __restrict__ b1,
    const float* __restrict__ a1, const float* __restrict__ c1,
    const float* __restrict__ W2, const float* __restrict__ b2,
    const float* __restrict__ a2, const float* __restrict__ c2,
    const float* __restrict__ W3, const float* __restrict__ b3,
    float* __restrict__ C)
{
    if (threadIdx.x == 0 && blockIdx.x == 0) {
        for (int j = 0; j < 8; ++j) {
            float ncl = c1[j] * NLOG2E;
            C[j]      = W1[j]     * ncl;
            C[8 + j]  = W1[8 + j] * ncl;
            C[16 + j] = b1[j]     * ncl;
            float k1 = a1[j] / ncl;
            for (int k = 0; k < 4; ++k)
                C[24 + j * 4 + k] = W2[j * 4 + k] * k1;
        }
        for (int k = 0; k < 4; ++k) {
            C[56 + k] = b2[k];
            C[60 + k] = c2[k] * NLOG2E;
            C[64 + k] = a2[k] * W3[k];
        }
        C[68] = b3[0];
    }
}

// invert 4 positive denominators with one rcp (product tree)
__device__ __forceinline__ void quad_inv(const float d[4], float inv[4]) {
    float p01  = d[0] * d[1];
    float p012 = p01  * d[2];
    float P    = p012 * d[3];
    float R    = __builtin_amdgcn_rcpf(P);
    float s23  = d[2] * d[3];
    inv[0] = (R * d[1]) * s23;
    inv[1] = (R * d[0]) * s23;
    inv[2] = (R * p01)  * d[3];
    inv[3] = R * p012;
}

__global__ __launch_bounds__(256, 4) void PlaygroundModel_66365834658304_kernel(
    const float* __restrict__ x, const float* __restrict__ C,
    float* __restrict__ out, int rows)
{
    const float* uw0  = C;
    const float* uw1  = C + 8;
    const float* ub   = C + 16;
    const float* w2f  = C + 24;
    const float* bb2  = C + 56;
    const float* ncl2 = C + 60;
    const float* aw2  = C + 64;
    float bb3 = C[68];

    int tid = blockIdx.x * blockDim.x + threadIdx.x;
    long long base = (long long)tid * 4;

    if (base + 3 < rows) {
        const float4* x4 = (const float4*)x;
        float4 p0 = x4[(size_t)tid * 2 + 0];
        float4 p1 = x4[(size_t)tid * 2 + 1];
        float X0[4] = {p0.x, p0.z, p1.x, p1.z};
        float X1[4] = {p0.y, p0.w, p1.y, p1.w};

        // stage 1: 32 independent u-values
        float uv[4][8];
#pragma unroll
        for (int r = 0; r < 4; ++r)
#pragma unroll
            for (int j = 0; j < 8; ++j)
                uv[r][j] = fmaf(X0[r], uw0[j], fmaf(X1[r], uw1[j], ub[j]));

        // stage 2: h_eff = u * rcp(1+exp2(u)); rcp batched 4-wide
#pragma unroll
        for (int r = 0; r < 4; ++r)
#pragma unroll
            for (int q = 0; q < 2; ++q) {
                float d[4], inv[4];
#pragma unroll
                for (int jj = 0; jj < 4; ++jj) {
                    float uc = fminf(uv[r][q * 4 + jj], 30.0f);
                    d[jj] = 1.0f + __builtin_amdgcn_exp2f(uc);
                }
                quad_inv(d, inv);
#pragma unroll
                for (int jj = 0; jj < 4; ++jj)
                    uv[r][q * 4 + jj] *= inv[jj];      // h_eff in place
            }

        // stage 3: 16 independent dot-8
        float t2[4][4];
#pragma unroll
        for (int r = 0; r < 4; ++r)
#pragma unroll
            for (int k = 0; k < 4; ++k) {
                float t = bb2[k];
#pragma unroll
                for (int j = 0; j < 8; ++j)
                    t = fmaf(uv[r][j], w2f[j * 4 + k], t);
                t2[r][k] = t;
            }

        // stage 4: per row, 4 activations with one batched rcp, then reduce
        float res[4];
#pragma unroll
        for (int r = 0; r < 4; ++r) {
            float d[4], inv[4];
#pragma unroll
            for (int k = 0; k < 4; ++k) {
                float u2 = fminf(ncl2[k] * t2[r][k], 30.0f);
                d[k] = 1.0f + __builtin_amdgcn_exp2f(u2);
            }
            quad_inv(d, inv);
            float o = bb3;
#pragma unroll
            for (int k = 0; k < 4; ++k)
                o = fmaf(t2[r][k] * inv[k], aw2[k], o);
            res[r] = o;
        }
        ((float4*)out)[tid] = make_float4(res[0], res[1], res[2], res[3]);
    } else if (base < rows) {
        // tail (not hit for B = 8388608)
        for (long long rr = base; rr < rows; ++rr) {
            float x0 = x[rr * 2 + 0], x1 = x[rr * 2 + 1];
            float h[8];
#pragma unroll
            for (int j = 0; j < 8; ++j) {
                float uu = fmaf(x0, uw0[j], fmaf(x1, uw1[j], ub[j]));
                float s  = __builtin_amdgcn_rcpf(
                               1.0f + __builtin_amdgcn_exp2f(fminf(uu, 30.0f)));
                h[j] = uu * s;
            }
            float o = bb3;
#pragma unroll
            for (int k = 0; k < 4; ++k) {
                float t = bb2[k];
#pragma unroll
                for (int j = 0; j < 8; ++j) t = fmaf(h[j], w2f[j * 4 + k], t);
                float u2 = fminf(ncl2[k] * t, 30.0f);
                float sg = __builtin_amdgcn_rcpf(
                               1.0f + __builtin_amdgcn_exp2f(u2));
                o = fmaf(t * sg, aw2[k], o);
            }
            out[rr] = o;
        }
    }
}

extern "C" void kernel_launch(void* const* d_in, const int* in_sizes, int n_in,
                              void* d_out, int out_size, void* d_ws, size_t ws_size,
                              hipStream_t stream) {
    const float* x  = (const float*)d_in[0];
    const float* W1 = (const float*)d_in[1];
    const float* b1 = (const float*)d_in[2];
    const float* a1 = (const float*)d_in[3];
    const float* c1 = (const float*)d_in[4];
    const float* W2 = (const float*)d_in[5];
    const float* b2 = (const float*)d_in[6];
    const float* a2 = (const float*)d_in[7];
    const float* c2 = (const float*)d_in[8];
    const float* W3 = (const float*)d_in[9];
    const float* b3 = (const float*)d_in[10];
    float* out = (float*)d_out;
    float* C   = (float*)d_ws;

    prefold_kernel<<<1, 64, 0, stream>>>(W1, b1, a1, c1, W2, b2, a2, c2,
                                         W3, b3, C);

    int rows  = in_sizes[0] / 2;
    int rows4 = (rows + 3) / 4;            // 4 rows per thread, one-shot
    int block = 256;
    int grid  = (rows4 + block - 1) / block;

    PlaygroundModel_66365834658304_kernel<<<grid, block, 0, stream>>>(
        x, C, out, rows);
}

// Round 8
// 125.467 us; speedup vs baseline: 1.0999x; 1.0325x over previous
//
#include <hip/hip_runtime.h>

#define NLOG2E -1.44269504088896340736f

typedef float f32x2 __attribute__((ext_vector_type(2)));

// K1 (1 thread): fold weight algebra into 69 floats in d_ws.
// K2: one-shot, 4 rows/thread, all FMA/mul/add stages written over float2
//     ext-vectors so the backend emits v_pk_fma_f32 / v_pk_mul_f32 /
//     v_pk_add_f32 (2 fp32 ops per lane per issue). Trans (exp2/rcp) stays
//     scalar per lane (no packed trans on CDNA4).
//
// ws layout (floats): [0:8)=uw0 [8:16)=uw1 [16:24)=ub [24:56)=w2f
//                     [56:60)=b2 [60:64)=ncl2 [64:68)=aw2 [68]=bb3
// All pair offsets are even -> 8B-aligned f32x2 reads.

__global__ void prefold_kernel(
    const float* __restrict__ W1, const float* __restrict__ b1,
    const float* __restrict__ a1, const float* __restrict__ c1,
    const float* __restrict__ W2, const float* __restrict__ b2,
    const float* __restrict__ a2, const float* __restrict__ c2,
    const float* __restrict__ W3, const float* __restrict__ b3,
    float* __restrict__ C)
{
    if (threadIdx.x == 0 && blockIdx.x == 0) {
        for (int j = 0; j < 8; ++j) {
            float ncl = c1[j] * NLOG2E;
            C[j]      = W1[j]     * ncl;
            C[8 + j]  = W1[8 + j] * ncl;
            C[16 + j] = b1[j]     * ncl;
            float k1 = a1[j] / ncl;
            for (int k = 0; k < 4; ++k)
                C[24 + j * 4 + k] = W2[j * 4 + k] * k1;
        }
        for (int k = 0; k < 4; ++k) {
            C[56 + k] = b2[k];
            C[60 + k] = c2[k] * NLOG2E;
            C[64 + k] = a2[k] * W3[k];
        }
        C[68] = b3[0];
    }
}

__global__ __launch_bounds__(256, 4) void PlaygroundModel_66365834658304_kernel(
    const float* __restrict__ x, const float* __restrict__ C,
    float* __restrict__ out, int rows)
{
    const f32x2* Cp  = (const f32x2*)C;
    // pair views of the constant block
    //   uw0 pairs: Cp[0..3]   uw1: Cp[4..7]   ub: Cp[8..11]
    //   w2f pairs: Cp[12 + j*2 + kp]  (j in [0,8), kp in {0,1})
    //   b2: Cp[28..29]  ncl2: Cp[30..31]  aw2: Cp[32..33]  bb3: C[68]
    float bb3 = C[68];

    int tid = blockIdx.x * blockDim.x + threadIdx.x;
    long long base = (long long)tid * 4;

    if (base + 3 < rows) {
        const float4* x4 = (const float4*)x;
        float4 p0 = x4[(size_t)tid * 2 + 0];
        float4 p1 = x4[(size_t)tid * 2 + 1];
        float X0[4] = {p0.x, p0.z, p1.x, p1.z};
        float X1[4] = {p0.y, p0.w, p1.y, p1.w};

        // stage 1: u-values, 4 rows x 4 j-pairs of pk_fma
        f32x2 u[4][4];
#pragma unroll
        for (int r = 0; r < 4; ++r) {
            f32x2 x0b = {X0[r], X0[r]};
            f32x2 x1b = {X1[r], X1[r]};
#pragma unroll
            for (int p = 0; p < 4; ++p)
                u[r][p] = __builtin_elementwise_fma(
                              x0b, Cp[p],
                              __builtin_elementwise_fma(x1b, Cp[4 + p],
                                                        Cp[8 + p]));
        }

        // stage 2: h_eff = u * rcp(1 + exp2(u)); trans scalar, rest packed
#pragma unroll
        for (int r = 0; r < 4; ++r)
#pragma unroll
            for (int p = 0; p < 4; ++p) {
                f32x2 e;
                e[0] = __builtin_amdgcn_exp2f(u[r][p][0]);
                e[1] = __builtin_amdgcn_exp2f(u[r][p][1]);
                f32x2 d = e + 1.0f;                    // pk_add
                f32x2 s;
                s[0] = __builtin_amdgcn_rcpf(d[0]);
                s[1] = __builtin_amdgcn_rcpf(d[1]);
                u[r][p] *= s;                          // pk_mul, h_eff
            }

        // stage 3: layer-2 dot-8, two k-pair accumulators per row
        f32x2 t2a[4], t2b[4];
#pragma unroll
        for (int r = 0; r < 4; ++r) {
            f32x2 ta = Cp[28], tb = Cp[29];            // b2 pairs
#pragma unroll
            for (int j = 0; j < 8; ++j) {
                float hj = u[r][j >> 1][j & 1];
                f32x2 hb = {hj, hj};
                ta = __builtin_elementwise_fma(hb, Cp[12 + j * 2 + 0], ta);
                tb = __builtin_elementwise_fma(hb, Cp[12 + j * 2 + 1], tb);
            }
            t2a[r] = ta; t2b[r] = tb;
        }

        // stage 4: second activation + final reduce, packed where possible
        float res[4];
#pragma unroll
        for (int r = 0; r < 4; ++r) {
            f32x2 u2a = Cp[30] * t2a[r];               // ncl2 pairs
            f32x2 u2b = Cp[31] * t2b[r];
            f32x2 ea, eb;
            ea[0] = __builtin_amdgcn_exp2f(u2a[0]);
            ea[1] = __builtin_amdgcn_exp2f(u2a[1]);
            eb[0] = __builtin_amdgcn_exp2f(u2b[0]);
            eb[1] = __builtin_amdgcn_exp2f(u2b[1]);
            f32x2 da = ea + 1.0f, db = eb + 1.0f;
            f32x2 sa, sb;
            sa[0] = __builtin_amdgcn_rcpf(da[0]);
            sa[1] = __builtin_amdgcn_rcpf(da[1]);
            sb[0] = __builtin_amdgcn_rcpf(db[0]);
            sb[1] = __builtin_amdgcn_rcpf(db[1]);
            f32x2 pa = t2a[r] * sa;                    // pk_mul
            f32x2 pb = t2b[r] * sb;
            f32x2 acc = {bb3, 0.0f};
            acc = __builtin_elementwise_fma(pa, Cp[32], acc);
            acc = __builtin_elementwise_fma(pb, Cp[33], acc);
            res[r] = acc[0] + acc[1];
        }
        ((float4*)out)[tid] = make_float4(res[0], res[1], res[2], res[3]);
    } else if (base < rows) {
        // tail (not hit for B = 8388608)
        const float* uw0  = C;
        const float* uw1  = C + 8;
        const float* ub   = C + 16;
        const float* w2f  = C + 24;
        const float* bb2  = C + 56;
        const float* ncl2 = C + 60;
        const float* aw2  = C + 64;
        for (long long rr = base; rr < rows; ++rr) {
            float x0 = x[rr * 2 + 0], x1 = x[rr * 2 + 1];
            float h[8];
#pragma unroll
            for (int j = 0; j < 8; ++j) {
                float uu = fmaf(x0, uw0[j], fmaf(x1, uw1[j], ub[j]));
                float s  = __builtin_amdgcn_rcpf(
                               1.0f + __builtin_amdgcn_exp2f(uu));
                h[j] = uu * s;
            }
            float o = bb3;
#pragma unroll
            for (int k = 0; k < 4; ++k) {
                float t = bb2[k];
#pragma unroll
                for (int j = 0; j < 8; ++j) t = fmaf(h[j], w2f[j * 4 + k], t);
                float u2 = ncl2[k] * t;
                float sg = __builtin_amdgcn_rcpf(
                               1.0f + __builtin_amdgcn_exp2f(u2));
                o = fmaf(t * sg, aw2[k], o);
            }
            out[rr] = o;
        }
    }
}

extern "C" void kernel_launch(void* const* d_in, const int* in_sizes, int n_in,
                              void* d_out, int out_size, void* d_ws, size_t ws_size,
                              hipStream_t stream) {
    const float* x  = (const float*)d_in[0];
    const float* W1 = (const float*)d_in[1];
    const float* b1 = (const float*)d_in[2];
    const float* a1 = (const float*)d_in[3];
    const float* c1 = (const float*)d_in[4];
    const float* W2 = (const float*)d_in[5];
    const float* b2 = (const float*)d_in[6];
    const float* a2 = (const float*)d_in[7];
    const float* c2 = (const float*)d_in[8];
    const float* W3 = (const float*)d_in[9];
    const float* b3 = (const float*)d_in[10];
    float* out = (float*)d_out;
    float* C   = (float*)d_ws;

    prefold_kernel<<<1, 64, 0, stream>>>(W1, b1, a1, c1, W2, b2, a2, c2,
                                         W3, b3, C);

    int rows  = in_sizes[0] / 2;
    int rows4 = (rows + 3) / 4;            // 4 rows/thread, one-shot
    int block = 256;
    int grid  = (rows4 + block - 1) / block;

    PlaygroundModel_66365834658304_kernel<<<grid, block, 0, stream>>>(
        x, C, out, rows);
}